// Round 1
// baseline (9636.033 us; speedup 1.0000x reference)
//
#include <hip/hip_runtime.h>
#include <math.h>

#define T_ 16
#define B_ 128
#define D_ 96
#define N_ 8
#define C3 24      // 3*N
#define REL_ 96
#define OUT_ 64
#define NT 768     // threads per block (12 waves)
#define TS 97      // padded row stride for s_t (breaks 8-way bank aliasing)
#define EPS_ 1e-5f

// ---------------- y0 = rel_bias @ Wr  (one-time, shared across batches) -------------
__global__ __launch_bounds__(NT, 1) void y0_kernel(const float* __restrict__ rel_bias,
                                                   const float* __restrict__ Wr,
                                                   float* __restrict__ y0) {
    __shared__ float s[NT];
    const int n = blockIdx.x;          // 0..7
    const int tid = threadIdx.x;
    const int r = tid % 96, p = tid / 96;   // p: 0..7
    const float* rb = rel_bias + n * 9216;
    float acc = 0.f;
    for (int i = p * 1152; i < (p + 1) * 1152; ++i)
        acc += rb[i] * Wr[(size_t)i * 96 + r];
    s[tid] = acc;
    __syncthreads();
    if (tid < 96) {
        float tot = 0.f;
        for (int q = 0; q < 8; ++q) tot += s[q * 96 + tid];
        y0[n * 96 + tid] = tot;
    }
}

// ---------------- main scan: one block per batch, persistent over T steps ----------
__global__ __launch_bounds__(NT, 3) void stm_kernel(
    const float* __restrict__ x, const float* __restrict__ Wqkv, const float* __restrict__ bqkv,
    const float* __restrict__ ln_g, const float* __restrict__ ln_b,
    const float* __restrict__ a1p, const float* __restrict__ a2p, const float* __restrict__ a3p,
    const float* __restrict__ W2, const float* __restrict__ b2,
    const float* __restrict__ Wr, const float* __restrict__ br,
    const float* __restrict__ W3, const float* __restrict__ b3,
    const float* __restrict__ item_bias, const float* __restrict__ rel_bias,
    const float* __restrict__ y0, float* __restrict__ out)
{
    __shared__ float s_Mi[9216];                 // Mi[e][f]
    __shared__ float s_S[9216];                  // S[d][e] = sum_n rel[n][d][e]
    __shared__ float s_qkv[2304];                // qkv[d][c], c in 0..23
    __shared__ float s_t[64 * TS];               // t[(n*8+j)*TS + d]
    __shared__ float s_tsum[768];                // tsum[j][d]
    __shared__ float s_v[768];                   // v[j][e]
    __shared__ float s_y[768];                   // y[n][r]
    __shared__ float s_rvec[768];
    __shared__ float s_xt[96];
    __shared__ float s_Vtr[96];
    __shared__ __attribute__((aligned(16))) float s_scr[6144];  // scratch: R0 chunk / G / reductions
    __shared__ float s_mu, s_rstd;

    const int tid = threadIdx.x;
    const int b = blockIdx.x;
    const float a1 = a1p[0], a2 = a2p[0], a3 = a3p[0];

    // ---- init state ----
    for (int i = tid; i < 9216; i += NT) {
        s_Mi[i] = item_bias[i];
        float ss = 0.f;
        for (int n = 0; n < 8; ++n) ss += rel_bias[n * 9216 + i];
        s_S[i] = ss;
    }
    s_y[tid] = y0[tid];
    __syncthreads();

    for (int t = 0; t < T_; ++t) {
        // ---- xt ----
        if (tid < 96) s_xt[tid] = x[((size_t)t * B_ + b) * 96 + tid];
        __syncthreads();
        // ---- Mi += xt xt^T ----
        for (int i = tid; i < 9216; i += NT)
            s_Mi[i] += s_xt[i / 96] * s_xt[i % 96];
        __syncthreads();
        // ---- Vtr[f] = sum_d Mi[d][f] * S[d][f] ----
        {
            const int f = tid % 96, p = tid / 96;
            float acc = 0.f;
            for (int d = p * 12; d < p * 12 + 12; ++d)
                acc += s_Mi[d * 96 + f] * s_S[d * 96 + f];
            s_scr[tid] = acc;
        }
        __syncthreads();
        if (tid < 96) {
            float acc = 0.f;
            for (int p = 0; p < 8; ++p) acc += s_scr[p * 96 + tid];
            s_Vtr[tid] = acc;
        }
        __syncthreads();
        // ---- qkv (pre-LN): qkv[i][j] = sum_k (Mi[i][k] + a2*Vtr[i]*xt[k]) * Wqkv[k][j] + bqkv[j]
        for (int pp = 0; pp < 3; ++pp) {
            const int o = tid + NT * pp;
            const int i = o / C3, j = o % C3;
            float acc = bqkv[j];
            const float a2v = a2 * s_Vtr[i];
            const float* mrow = s_Mi + i * 96;
            for (int k = 0; k < 96; ++k)
                acc += (mrow[k] + a2v * s_xt[k]) * Wqkv[k * C3 + j];
            s_qkv[o] = acc;
        }
        __syncthreads();
        // ---- LayerNorm over all 2304 ----
        {
            float ls = 0.f, lq = 0.f;
            for (int pp = 0; pp < 3; ++pp) { const float v = s_qkv[tid + NT * pp]; ls += v; lq += v * v; }
            for (int off = 32; off > 0; off >>= 1) {
                ls += __shfl_down(ls, off);
                lq += __shfl_down(lq, off);
            }
            const int lane = tid & 63, wid = tid >> 6;
            if (lane == 0) { s_scr[wid] = ls; s_scr[32 + wid] = lq; }
        }
        __syncthreads();
        if (tid == 0) {
            float S = 0.f, Q = 0.f;
            for (int w = 0; w < 12; ++w) { S += s_scr[w]; Q += s_scr[32 + w]; }
            const float mu = S * (1.0f / 2304.f);
            const float var = Q * (1.0f / 2304.f) - mu * mu;
            s_mu = mu; s_rstd = rsqrtf(var + EPS_);
        }
        __syncthreads();
        {
            const float mu = s_mu, rstd = s_rstd;
            for (int pp = 0; pp < 3; ++pp) {
                const int o = tid + NT * pp;
                s_qkv[o] = (s_qkv[o] - mu) * rstd * ln_g[o] + ln_b[o];
            }
        }
        __syncthreads();
        // ---- v copy + t = tanh(q*k) ----
        { const int j = tid / 96, e = tid % 96; s_v[tid] = s_qkv[e * C3 + 16 + j]; }
        for (int pp = 0; pp < 8; ++pp) {
            const int o = tid + NT * pp;           // 6144 items
            const int d = o % 96, nj = o / 96;
            const int n = nj >> 3, j = nj & 7;
            s_t[(n * 8 + j) * TS + d] = tanhf(s_qkv[d * C3 + n] * s_qkv[d * C3 + 8 + j]);
        }
        __syncthreads();
        // ---- tsum[j][d] = sum_n t[n][j][d] ; G[j][f] = sum_{n,d} t[n][j][d]*W2[(n*96+d)*96+f]
        {
            const int j = tid / 96, df = tid % 96;
            float acc = 0.f;
            for (int n = 0; n < 8; ++n) acc += s_t[(n * 8 + j) * TS + df];
            s_tsum[tid] = acc;
            float g = 0.f;
            const float* trow = s_t + j * TS;
            for (int n = 0; n < 8; ++n)
                for (int d = 0; d < 96; ++d)
                    g += trow[n * 8 * TS + d] * W2[(size_t)(n * 96 + d) * 96 + df];
            s_scr[tid] = g;                        // G in scr[0..768)
        }
        __syncthreads();
        // ---- S update and Mi += a3*R2 (R2[e][f] = sum_j v[j][e]*G[j][f] + b2[f]) ----
        for (int pp = 0; pp < 12; ++pp) {
            const int i = tid + NT * pp;           // over 9216
            const int de = i / 96, ef = i % 96;
            float sn = 0.f, r2 = b2[ef];
#pragma unroll
            for (int j = 0; j < 8; ++j) {
                sn += s_tsum[j * 96 + de] * s_v[j * 96 + ef];
                r2 += s_v[j * 96 + de] * s_scr[j * 96 + ef];
            }
            s_S[i] = a1 * s_S[i] + sn;
            s_Mi[i] += a3 * r2;
        }
        __syncthreads();
        // ---- heavy: y_delta[n][r] = sum_{d,e} R0[n,d,e]*Wr[(d*96+e)*96+r] ----
        {
            const int rq = tid % 24, p = tid / 24;   // p: 0..31 contraction partition
            float acc[8][4];
#pragma unroll
            for (int n = 0; n < 8; ++n)
#pragma unroll
                for (int c = 0; c < 4; ++c) acc[n][c] = 0.f;

            for (int ch = 0; ch < 12; ++ch) {
                const int d0 = ch * 8;
                // build R0 chunk, layout scr[(dc*96+e)*8 + n] (n contiguous)
                for (int pp = 0; pp < 8; ++pp) {
                    const int o = tid + NT * pp;     // 6144 items
                    const int n = o & 7;
                    const int xi = o >> 3;           // 0..767
                    const int e = xi % 96, dc = xi / 96;
                    float r0 = 0.f;
#pragma unroll
                    for (int j = 0; j < 8; ++j)
                        r0 += s_t[(n * 8 + j) * TS + d0 + dc] * s_v[j * 96 + e];
                    s_scr[xi * 8 + n] = r0;
                }
                __syncthreads();
                // accumulate 24 contraction indices for this thread
                for (int s = 0; s < 24; ++s) {
                    const int i = p * 24 + s;        // (dc*96+e)
                    const float4 r0a = ((const float4*)s_scr)[i * 2];
                    const float4 r0b = ((const float4*)s_scr)[i * 2 + 1];
                    const float4 w = *(const float4*)(Wr + ((size_t)(d0 * 96 + i)) * 96 + rq * 4);
                    const float rn[8] = {r0a.x, r0a.y, r0a.z, r0a.w, r0b.x, r0b.y, r0b.z, r0b.w};
                    const float wv[4] = {w.x, w.y, w.z, w.w};
#pragma unroll
                    for (int n = 0; n < 8; ++n)
#pragma unroll
                        for (int c = 0; c < 4; ++c)
                            acc[n][c] += rn[n] * wv[c];
                }
                __syncthreads();
            }
            // reduce partials over p (32) and update y
#pragma unroll 1
            for (int n = 0; n < 8; ++n) {
                ((float4*)s_scr)[p * 24 + rq] = make_float4(acc[n][0], acc[n][1], acc[n][2], acc[n][3]);
                __syncthreads();
                if (tid < 96) {
                    float tot = 0.f;
                    for (int q = 0; q < 32; ++q) tot += s_scr[q * 96 + tid];
                    s_y[n * 96 + tid] = a1 * s_y[n * 96 + tid] + tot;
                }
                __syncthreads();
            }
        }
        // ---- r_vec = y + br ; out = r_vec @ W3 + b3 ----
        s_rvec[tid] = s_y[tid] + br[tid % 96];
        __syncthreads();
        {
            const int o = tid % 64, q = tid / 64;    // q: 0..11
            float acc = 0.f;
            for (int i = q * 64; i < q * 64 + 64; ++i)
                acc += s_rvec[i] * W3[(size_t)i * 64 + o];
            s_scr[tid] = acc;
        }
        __syncthreads();
        if (tid < 64) {
            float acc = b3[tid];
            for (int q = 0; q < 12; ++q) acc += s_scr[q * 64 + tid];
            out[((size_t)t * B_ + b) * OUT_ + tid] = acc;
        }
        __syncthreads();
    }
}

extern "C" void kernel_launch(void* const* d_in, const int* in_sizes, int n_in,
                              void* d_out, int out_size, void* d_ws, size_t ws_size,
                              hipStream_t stream) {
    const float* x         = (const float*)d_in[0];
    const float* Wqkv      = (const float*)d_in[1];
    const float* bqkv      = (const float*)d_in[2];
    const float* ln_g      = (const float*)d_in[3];
    const float* ln_b      = (const float*)d_in[4];
    const float* a1        = (const float*)d_in[5];
    const float* a2        = (const float*)d_in[6];
    const float* a3        = (const float*)d_in[7];
    const float* W2        = (const float*)d_in[8];
    const float* b2        = (const float*)d_in[9];
    const float* Wr        = (const float*)d_in[10];
    const float* br        = (const float*)d_in[11];
    const float* W3        = (const float*)d_in[12];
    const float* b3        = (const float*)d_in[13];
    const float* item_bias = (const float*)d_in[14];
    const float* rel_bias  = (const float*)d_in[15];
    float* out = (float*)d_out;
    float* y0  = (float*)d_ws;   // 768 floats

    hipLaunchKernelGGL(y0_kernel, dim3(8), dim3(NT), 0, stream, rel_bias, Wr, y0);
    hipLaunchKernelGGL(stm_kernel, dim3(B_), dim3(NT), 0, stream,
                       x, Wqkv, bqkv, ln_g, ln_b, a1, a2, a3,
                       W2, b2, Wr, br, W3, b3, item_bias, rel_bias, y0, out);
}

// Round 3
// 2896.370 us; speedup vs baseline: 3.3269x; 3.3269x over previous
//
#include <hip/hip_runtime.h>
#include <math.h>

#define T_ 16
#define B_ 128
#define C3 24
#define OUT_ 64
#define NT 768
#define EPS_ 1e-5f
#define TPs 776      // s_tP row stride (dwords)
#define CHs 772      // chunk row stride (dwords)

typedef __attribute__((ext_vector_type(8))) short bf16x8;
typedef __attribute__((ext_vector_type(4))) float f32x4;

union FragU { unsigned u[4]; bf16x8 f; };

// pack fp32 -> (bf16_hi << 16) | bf16_lo(residual), both RNE: ~17-bit significand
__device__ __forceinline__ unsigned packsplit(float x) {
    unsigned u = __float_as_uint(x);
    unsigned h = (u + 0x7fffu + ((u >> 16) & 1u)) & 0xffff0000u;
    float r = x - __uint_as_float(h);
    unsigned v = __float_as_uint(r);
    unsigned l = (v + 0x7fffu + ((v >> 16) & 1u)) >> 16;
    return h | l;
}
__device__ __forceinline__ float unpack2f(unsigned p) {
    return __uint_as_float(p & 0xffff0000u) + __uint_as_float(p << 16);
}
__device__ __forceinline__ void unpack_frags(const unsigned* p, bf16x8& hi, bf16x8& lo) {
    FragU H, L;
#pragma unroll
    for (int q = 0; q < 4; ++q) {
        H.u[q] = (p[2*q] >> 16) | (p[2*q+1] & 0xffff0000u);
        L.u[q] = (p[2*q] & 0xffffu) | (p[2*q+1] << 16);
    }
    hi = H.f; lo = L.f;
}
__device__ __forceinline__ f32x4 mfma16(bf16x8 a, bf16x8 b, f32x4 c) {
    return __builtin_amdgcn_mfma_f32_16x16x32_bf16(a, b, c, 0, 0, 0);
}

// ---------- prep: WrP[r][k] = packsplit(Wr[k][r]), r<96, k<9216 ----------
__global__ void prep_pack_wr(const float* __restrict__ Wr, unsigned* __restrict__ WrP) {
    int idx = blockIdx.x * 256 + threadIdx.x;
    if (idx >= 9216 * 96) return;
    int r = idx / 9216, k = idx % 9216;
    WrP[idx] = packsplit(Wr[(size_t)k * 96 + r]);
}
// ---------- prep: W2P[f][k] = packsplit(W2[k][f]), f<96, k<768 ----------
__global__ void prep_pack_w2(const float* __restrict__ W2, unsigned* __restrict__ W2P) {
    int idx = blockIdx.x * 256 + threadIdx.x;
    if (idx >= 768 * 96) return;
    int f = idx / 768, k = idx % 768;
    W2P[idx] = packsplit(W2[(size_t)k * 96 + f]);
}
// ---------- prep: y0 = rel_bias @ Wr (fp32) ----------
__global__ __launch_bounds__(NT, 1) void y0_kernel(const float* __restrict__ rel_bias,
                                                   const float* __restrict__ Wr,
                                                   float* __restrict__ y0) {
    __shared__ float s[NT];
    const int n = blockIdx.x;
    const int tid = threadIdx.x;
    const int r = tid % 96, p = tid / 96;
    const float* rb = rel_bias + n * 9216;
    float acc = 0.f;
    for (int i = p * 1152; i < (p + 1) * 1152; ++i)
        acc += rb[i] * Wr[(size_t)i * 96 + r];
    s[tid] = acc;
    __syncthreads();
    if (tid < 96) {
        float tot = 0.f;
        for (int q = 0; q < 8; ++q) tot += s[q * 96 + tid];
        y0[n * 96 + tid] = tot;
    }
}

// ---------------- main scan: one block per batch ----------------
__global__ __launch_bounds__(NT, 3) void stm_kernel(
    const float* __restrict__ x, const float* __restrict__ Wqkv, const float* __restrict__ bqkv,
    const float* __restrict__ ln_g, const float* __restrict__ ln_b,
    const float* __restrict__ a1p, const float* __restrict__ a2p, const float* __restrict__ a3p,
    const float* __restrict__ b2, const float* __restrict__ br,
    const float* __restrict__ W3, const float* __restrict__ b3,
    const float* __restrict__ item_bias, const float* __restrict__ rel_bias,
    const float* __restrict__ y0g, const unsigned* __restrict__ WrP, const unsigned* __restrict__ W2P,
    float* __restrict__ out)
{
    __shared__ float s_Mi[9216];
    __shared__ float s_S[9216];
    __shared__ float s_Q[2304];                       // Q = Mi @ Wqkv (incremental)
    __shared__ __attribute__((aligned(16))) unsigned s_scr[6176]; // union: qkv | partials | R0 chunk | reductions
    __shared__ __attribute__((aligned(16))) unsigned s_tP[8 * TPs]; // packed-split t: [j][n*96+d]
    __shared__ float s_tsum[768];                     // [j][d]  (EXACT fp32)
    __shared__ float s_v[768];                        // [j][e]
    __shared__ float s_G[768];                        // [j][f]
    __shared__ float s_y[768];                        // [n][r]
    __shared__ float s_xt[96];
    __shared__ float s_xtWq[24];
    __shared__ float s_GWq[192];
    __shared__ float s_b2Wq[24];
    __shared__ float s_Vtr[96];
    __shared__ float s_br[96];
    __shared__ float s_red[32];
    __shared__ float s_mu, s_rstd;

    const int tid = threadIdx.x;
    const int b = blockIdx.x;
    const int wv = tid >> 6, lane = tid & 63, col = lane & 15, grp = lane >> 4;
    const float a1 = a1p[0], a2 = a2p[0], a3 = a3p[0];
    float* scr = (float*)s_scr;
    unsigned* chP = s_scr;

    // ---- init ----
    for (int i = tid; i < 9216; i += NT) {
        s_Mi[i] = item_bias[i];
        float ss = 0.f;
        for (int n = 0; n < 8; ++n) ss += rel_bias[n * 9216 + i];
        s_S[i] = ss;
    }
    s_y[tid] = y0g[tid];
    if (tid < 96) s_br[tid] = br[tid];
    // Q0 = item_bias @ Wqkv
    for (int pp = 0; pp < 3; ++pp) {
        int o = tid + NT * pp; int i = o / C3, c = o % C3;
        float acc = 0.f;
        const float* ib = item_bias + i * 96;
        for (int k = 0; k < 96; ++k) acc += ib[k] * Wqkv[k * C3 + c];
        s_Q[o] = acc;
    }
    { // b2Wq partials
        int c = tid % C3, p = tid / C3; float acc = 0.f;
        for (int k = 3 * p; k < 3 * p + 3; ++k) acc += b2[k] * Wqkv[k * C3 + c];
        scr[tid] = acc;
    }
    __syncthreads();
    if (tid < C3) { float a = 0.f; for (int p = 0; p < 32; ++p) a += scr[p * C3 + tid]; s_b2Wq[tid] = a; }
    __syncthreads();

    const int gB = tid / 12, sub = tid % 12;
    const int bn = gB >> 3, dl = gB & 7, e0 = sub * 8;

    for (int t = 0; t < T_; ++t) {
        // 1: xt
        if (tid < 96) s_xt[tid] = x[((size_t)t * B_ + b) * 96 + tid];
        __syncthreads();
        // 2: Mi += xt xt^T ; xtWq partials
        for (int p = 0; p < 12; ++p) { int i = tid + NT * p; s_Mi[i] += s_xt[i / 96] * s_xt[i % 96]; }
        { int c = tid % C3, p = tid / C3; float acc = 0.f;
          for (int k = 3 * p; k < 3 * p + 3; ++k) acc += s_xt[k] * Wqkv[k * C3 + c];
          scr[tid] = acc; }
        __syncthreads();
        // 3: xtWq final ; Vtr partials
        if (tid < C3) { float a = 0.f; for (int p = 0; p < 32; ++p) a += scr[p * C3 + tid]; s_xtWq[tid] = a; }
        { int f = tid % 96, p = tid / 96; float acc = 0.f;
          for (int d = p * 12; d < p * 12 + 12; ++d) acc += s_Mi[d * 96 + f] * s_S[d * 96 + f];
          scr[768 + tid] = acc; }
        __syncthreads();
        // 4: Vtr final ; Q += xt ⊗ xtWq
        if (tid < 96) { float a = 0.f; for (int p = 0; p < 8; ++p) a += scr[768 + p * 96 + tid]; s_Vtr[tid] = a; }
        for (int pp = 0; pp < 3; ++pp) { int o = tid + NT * pp; int i = o / C3, c = o % C3;
            s_Q[o] += s_xt[i] * s_xtWq[c]; }
        __syncthreads();
        // 5: qkv_pre -> scr[0..2304) + LN sums
        {
            float ls = 0.f, lq = 0.f;
            for (int pp = 0; pp < 3; ++pp) {
                int o = tid + NT * pp; int i = o / C3, c = o % C3;
                float q = s_Q[o] + a2 * s_Vtr[i] * s_xtWq[c] + bqkv[c];
                scr[o] = q; ls += q; lq += q * q;
            }
            for (int off = 32; off > 0; off >>= 1) { ls += __shfl_down(ls, off); lq += __shfl_down(lq, off); }
            if (lane == 0) { s_red[wv] = ls; s_red[16 + wv] = lq; }
        }
        __syncthreads();
        if (tid == 0) {
            float S = 0.f, Qs = 0.f;
            for (int w = 0; w < 12; ++w) { S += s_red[w]; Qs += s_red[16 + w]; }
            float mu = S * (1.0f / 2304.f);
            float var = Qs * (1.0f / 2304.f) - mu * mu;
            s_mu = mu; s_rstd = rsqrtf(var + EPS_);
        }
        __syncthreads();
        // 7: LN apply in-place
        { float mu = s_mu, rs = s_rstd;
          for (int pp = 0; pp < 3; ++pp) { int o = tid + NT * pp;
              scr[o] = (scr[o] - mu) * rs * ln_g[o] + ln_b[o]; } }
        __syncthreads();
        // 8: v copy + t (fp32 tanh, EXACT fp32 tsum, packed-split store)
        { int j = tid / 96, e = tid % 96; s_v[tid] = scr[e * C3 + 16 + j]; }
        {
            int j = tid / 96, d = tid % 96;
            float kk = scr[d * C3 + 8 + j];
            float ts = 0.f;
#pragma unroll
            for (int n = 0; n < 8; ++n) {
                float tv = tanhf(scr[d * C3 + n] * kk);
                ts += tv;
                s_tP[j * TPs + n * 96 + d] = packsplit(tv);
            }
            s_tsum[j * 96 + d] = ts;
        }
        __syncthreads();
        // 9: G-GEMM via split MFMA (4 terms), two-phase write to s_G
        {
            const int rt = wv % 6, kh = wv / 6;
            f32x4 accG = {0.f, 0.f, 0.f, 0.f};
            const unsigned* BP = W2P + (size_t)(rt * 16 + col) * 768;
#pragma unroll 2
            for (int s2 = 0; s2 < 12; ++s2) {
                int ko = (kh * 12 + s2) * 32 + grp * 8;
                unsigned pa[8] = {0,0,0,0,0,0,0,0};
                if (col < 8) {
                    const uint4* q0 = (const uint4*)&s_tP[col * TPs + ko];
                    uint4 x0 = q0[0], x1 = q0[1];
                    pa[0]=x0.x; pa[1]=x0.y; pa[2]=x0.z; pa[3]=x0.w;
                    pa[4]=x1.x; pa[5]=x1.y; pa[6]=x1.z; pa[7]=x1.w;
                }
                bf16x8 ah, al; unpack_frags(pa, ah, al);
                unsigned pb[8];
                { const uint4* qb = (const uint4*)&BP[ko];
                  uint4 z0 = qb[0], z1 = qb[1];
                  pb[0]=z0.x; pb[1]=z0.y; pb[2]=z0.z; pb[3]=z0.w;
                  pb[4]=z1.x; pb[5]=z1.y; pb[6]=z1.z; pb[7]=z1.w; }
                bf16x8 bh, bl; unpack_frags(pb, bh, bl);
                accG = mfma16(ah, bh, accG);
                accG = mfma16(al, bh, accG);
                accG = mfma16(ah, bl, accG);
                accG = mfma16(al, bl, accG);
            }
            if (kh == 0 && grp < 2) {
#pragma unroll
                for (int reg = 0; reg < 4; ++reg)
                    s_G[(grp * 4 + reg) * 96 + rt * 16 + col] = accG[reg];
            }
            __syncthreads();
            if (kh == 1 && grp < 2) {
#pragma unroll
                for (int reg = 0; reg < 4; ++reg)
                    s_G[(grp * 4 + reg) * 96 + rt * 16 + col] += accG[reg];
            }
        }
        __syncthreads();
        // 10: GWq partials (scr[0..768), qkv dead) + S/Mi updates (all fp32)
        { int oo = tid % 192, p = tid / 192; int jg = oo / C3, cc = oo % C3;
          float a = 0.f;
          for (int f = p * 24; f < p * 24 + 24; ++f) a += s_G[jg * 96 + f] * Wqkv[f * C3 + cc];
          scr[tid] = a; }
        {
            int de = tid >> 3, ef0 = (tid & 7) * 12;
            float tj[8], vj[8];
#pragma unroll
            for (int j = 0; j < 8; ++j) { tj[j] = s_tsum[j * 96 + de]; vj[j] = s_v[j * 96 + de]; }
            float sn[12], r2[12];
#pragma unroll
            for (int ii = 0; ii < 12; ++ii) { sn[ii] = 0.f; r2[ii] = b2[ef0 + ii]; }
#pragma unroll
            for (int j = 0; j < 8; ++j) {
                const float4* vp = (const float4*)&s_v[j * 96 + ef0];
                const float4* gp = (const float4*)&s_G[j * 96 + ef0];
#pragma unroll
                for (int q4 = 0; q4 < 3; ++q4) {
                    float4 vv = vp[q4], gg = gp[q4];
                    sn[q4 * 4 + 0] += tj[j] * vv.x; sn[q4 * 4 + 1] += tj[j] * vv.y;
                    sn[q4 * 4 + 2] += tj[j] * vv.z; sn[q4 * 4 + 3] += tj[j] * vv.w;
                    r2[q4 * 4 + 0] += vj[j] * gg.x; r2[q4 * 4 + 1] += vj[j] * gg.y;
                    r2[q4 * 4 + 2] += vj[j] * gg.z; r2[q4 * 4 + 3] += vj[j] * gg.w;
                }
            }
#pragma unroll
            for (int ii = 0; ii < 12; ++ii) {
                int idx = de * 96 + ef0 + ii;
                s_S[idx] = a1 * s_S[idx] + sn[ii];
                s_Mi[idx] += a3 * r2[ii];
            }
        }
        __syncthreads();
        // 11: GWq final
        if (tid < 192) s_GWq[tid] = scr[tid] + scr[192 + tid] + scr[384 + tid] + scr[576 + tid];
        __syncthreads();
        // 12: Q += a3*(v^T GWq + b2Wq)
        for (int pp = 0; pp < 3; ++pp) {
            int o = tid + NT * pp; int i = o / C3, c = o % C3;
            float a = s_b2Wq[c];
#pragma unroll
            for (int j = 0; j < 8; ++j) a += s_v[j * 96 + i] * s_GWq[j * C3 + c];
            s_Q[o] += a3 * a;
        }
        // ---- heavy: y += R0 @ Wr via split MFMA, 12 chunks of 8 d's ----
        f32x4 acc[6];
#pragma unroll
        for (int rt = 0; rt < 6; ++rt) acc[rt] = (f32x4){0.f, 0.f, 0.f, 0.f};
        float rr[8];
        auto build = [&](int ch) {
            int d = ch * 8 + dl;
            float tj[8];
#pragma unroll
            for (int j = 0; j < 8; ++j) tj[j] = unpack2f(s_tP[j * TPs + bn * 96 + d]);
#pragma unroll
            for (int i = 0; i < 8; ++i) rr[i] = 0.f;
#pragma unroll
            for (int j = 0; j < 8; ++j) {
                float4 v0 = *(const float4*)&s_v[j * 96 + e0];
                float4 v1 = *(const float4*)&s_v[j * 96 + e0 + 4];
                rr[0] += tj[j] * v0.x; rr[1] += tj[j] * v0.y; rr[2] += tj[j] * v0.z; rr[3] += tj[j] * v0.w;
                rr[4] += tj[j] * v1.x; rr[5] += tj[j] * v1.y; rr[6] += tj[j] * v1.z; rr[7] += tj[j] * v1.w;
            }
        };
        auto store_chunk = [&]() {
            uint4 u0, u1;
            u0.x = packsplit(rr[0]); u0.y = packsplit(rr[1]); u0.z = packsplit(rr[2]); u0.w = packsplit(rr[3]);
            u1.x = packsplit(rr[4]); u1.y = packsplit(rr[5]); u1.z = packsplit(rr[6]); u1.w = packsplit(rr[7]);
            uint4* dst = (uint4*)&chP[bn * CHs + dl * 96 + e0];
            dst[0] = u0; dst[1] = u1;
        };
        build(0);
        __syncthreads();
        store_chunk();
        __syncthreads();
        for (int ch = 0; ch < 12; ++ch) {
#pragma unroll
            for (int i2 = 0; i2 < 2; ++i2) {
                int kl = (wv * 2 + i2) * 32 + grp * 8;
                unsigned pa[8] = {0,0,0,0,0,0,0,0};
                if (col < 8) {
                    const uint4* q0 = (const uint4*)&chP[col * CHs + kl];
                    uint4 x0 = q0[0], x1 = q0[1];
                    pa[0]=x0.x; pa[1]=x0.y; pa[2]=x0.z; pa[3]=x0.w;
                    pa[4]=x1.x; pa[5]=x1.y; pa[6]=x1.z; pa[7]=x1.w;
                }
                bf16x8 ah, al; unpack_frags(pa, ah, al);
#pragma unroll
                for (int rt = 0; rt < 6; ++rt) {
                    unsigned pb[8];
                    const uint4* qb = (const uint4*)&WrP[(size_t)(rt * 16 + col) * 9216 + ch * 768 + kl];
                    uint4 z0 = qb[0], z1 = qb[1];
                    pb[0]=z0.x; pb[1]=z0.y; pb[2]=z0.z; pb[3]=z0.w;
                    pb[4]=z1.x; pb[5]=z1.y; pb[6]=z1.z; pb[7]=z1.w;
                    bf16x8 bh, bl; unpack_frags(pb, bh, bl);
                    acc[rt] = mfma16(ah, bh, acc[rt]);
                    acc[rt] = mfma16(al, bh, acc[rt]);
                    acc[rt] = mfma16(ah, bl, acc[rt]);
                    acc[rt] = mfma16(al, bl, acc[rt]);
                }
            }
            if (ch < 11) build(ch + 1);
            __syncthreads();
            if (ch < 11) { store_chunk(); __syncthreads(); }
        }
        // reduce 12 wave-partials (rows 0..7) into y
        if (wv < 6 && grp < 2) {
#pragma unroll
            for (int rt = 0; rt < 6; ++rt)
#pragma unroll
                for (int reg = 0; reg < 4; ++reg)
                    scr[(wv * 8 + grp * 4 + reg) * 96 + rt * 16 + col] = acc[rt][reg];
        }
        __syncthreads();
        if (wv >= 6 && grp < 2) {
#pragma unroll
            for (int rt = 0; rt < 6; ++rt)
#pragma unroll
                for (int reg = 0; reg < 4; ++reg)
                    scr[((wv - 6) * 8 + grp * 4 + reg) * 96 + rt * 16 + col] += acc[rt][reg];
        }
        __syncthreads();
        { int n = tid / 96, r = tid % 96; float a = 0.f;
          for (int w = 0; w < 6; ++w) a += scr[(w * 8 + n) * 96 + r];
          s_y[tid] = a1 * s_y[tid] + a; }
        __syncthreads();
        // out = (y + br) @ W3 + b3
        { int o = tid & 63, qq = tid >> 6; float a = 0.f;
          for (int i = qq * 64; i < qq * 64 + 64; ++i)
              a += (s_y[i] + s_br[i % 96]) * W3[(size_t)i * 64 + o];
          scr[tid] = a; }
        __syncthreads();
        if (tid < 64) {
            float a = b3[tid];
            for (int q = 0; q < 12; ++q) a += scr[q * 64 + tid];
            out[((size_t)t * B_ + b) * OUT_ + tid] = a;
        }
        __syncthreads();
    }
}

extern "C" void kernel_launch(void* const* d_in, const int* in_sizes, int n_in,
                              void* d_out, int out_size, void* d_ws, size_t ws_size,
                              hipStream_t stream) {
    const float* x         = (const float*)d_in[0];
    const float* Wqkv      = (const float*)d_in[1];
    const float* bqkv      = (const float*)d_in[2];
    const float* ln_g      = (const float*)d_in[3];
    const float* ln_b      = (const float*)d_in[4];
    const float* a1        = (const float*)d_in[5];
    const float* a2        = (const float*)d_in[6];
    const float* a3        = (const float*)d_in[7];
    const float* W2        = (const float*)d_in[8];
    const float* b2        = (const float*)d_in[9];
    const float* Wr        = (const float*)d_in[10];
    const float* br        = (const float*)d_in[11];
    const float* W3        = (const float*)d_in[12];
    const float* b3        = (const float*)d_in[13];
    const float* item_bias = (const float*)d_in[14];
    const float* rel_bias  = (const float*)d_in[15];
    float* out = (float*)d_out;

    char* ws = (char*)d_ws;
    unsigned* WrP = (unsigned*)ws;                         // 3,538,944 B
    unsigned* W2P = (unsigned*)(ws + 3538944);             //   294,912 B
    float*    y0  = (float*)(ws + 3538944 + 294912);       //     3,072 B

    hipLaunchKernelGGL(prep_pack_wr, dim3(3456), dim3(256), 0, stream, Wr, WrP);
    hipLaunchKernelGGL(prep_pack_w2, dim3(288), dim3(256), 0, stream, W2, W2P);
    hipLaunchKernelGGL(y0_kernel, dim3(8), dim3(NT), 0, stream, rel_bias, Wr, y0);
    hipLaunchKernelGGL(stm_kernel, dim3(B_), dim3(NT), 0, stream,
                       x, Wqkv, bqkv, ln_g, ln_b, a1, a2, a3,
                       b2, br, W3, b3, item_bias, rel_bias,
                       y0, WrP, W2P, out);
}

// Round 4
// 2574.458 us; speedup vs baseline: 3.7429x; 1.1250x over previous
//
#include <hip/hip_runtime.h>
#include <math.h>

#define T_ 16
#define B_ 128
#define C3 24
#define OUT_ 64
#define NT 768
#define EPS_ 1e-5f
#define TPs 776      // s_tP row stride (dwords)
#define CBS 3456     // chunk buffer size (dwords): 12 kb * 288
#define KBR 288      // per-kb stride in chunk buffer (8 cols * 36)
#define CS 36        // per-col stride in chunk buffer

typedef __attribute__((ext_vector_type(8))) short bf16x8;
typedef __attribute__((ext_vector_type(4))) float f32x4;

union FragU { unsigned u[4]; bf16x8 f; };

// fp32 -> (bf16_hi << 16) | bf16_lo(residual), both RNE
__device__ __forceinline__ unsigned packsplit(float x) {
    unsigned u = __float_as_uint(x);
    unsigned h = (u + 0x7fffu + ((u >> 16) & 1u)) & 0xffff0000u;
    float r = x - __uint_as_float(h);
    unsigned v = __float_as_uint(r);
    unsigned l = (v + 0x7fffu + ((v >> 16) & 1u)) >> 16;
    return h | l;
}
__device__ __forceinline__ float unpack2f(unsigned p) {
    return __uint_as_float(p & 0xffff0000u) + __uint_as_float(p << 16);
}
__device__ __forceinline__ void unpack_frags(const unsigned* p, bf16x8& hi, bf16x8& lo) {
    FragU H, L;
#pragma unroll
    for (int q = 0; q < 4; ++q) {
        H.u[q] = (p[2*q] >> 16) | (p[2*q+1] & 0xffff0000u);
        L.u[q] = (p[2*q] & 0xffffu) | (p[2*q+1] << 16);
    }
    hi = H.f; lo = L.f;
}
__device__ __forceinline__ f32x4 mfma16(bf16x8 a, bf16x8 b, f32x4 c) {
    return __builtin_amdgcn_mfma_f32_16x16x32_bf16(a, b, c, 0, 0, 0);
}

// ---------- prep: Wr -> fragment-major hi/lo planes ----------
// plane[((rt*288 + kb)*64 + lane)*8 + j] = bf16 of Wr[k][r], r=rt*16+col, k=kb*32+grp*8+j
__global__ void prep_wrf(const float* __restrict__ Wr, short* __restrict__ Fhi, short* __restrict__ Flo) {
    int idx = blockIdx.x * 256 + threadIdx.x;
    if (idx >= 884736) return;
    int j = idx & 7, lane = (idx >> 3) & 63, kb = (idx >> 9) % 288, rt = idx / (512 * 288);
    int col = lane & 15, grp = lane >> 4;
    int r = rt * 16 + col, k = kb * 32 + grp * 8 + j;
    float x = Wr[(size_t)k * 96 + r];
    unsigned u = __float_as_uint(x);
    unsigned h = (u + 0x7fffu + ((u >> 16) & 1u)) & 0xffff0000u;
    float res = x - __uint_as_float(h);
    unsigned v = __float_as_uint(res);
    Fhi[idx] = (short)(h >> 16);
    Flo[idx] = (short)((v + 0x7fffu + ((v >> 16) & 1u)) >> 16);
}
// ---------- prep: W2 -> fragment-major hi/lo planes (24 kb) ----------
__global__ void prep_w2f(const float* __restrict__ W2, short* __restrict__ Fhi, short* __restrict__ Flo) {
    int idx = blockIdx.x * 256 + threadIdx.x;
    if (idx >= 73728) return;
    int j = idx & 7, lane = (idx >> 3) & 63, kb = (idx >> 9) % 24, rt = idx / (512 * 24);
    int col = lane & 15, grp = lane >> 4;
    int f = rt * 16 + col, k = kb * 32 + grp * 8 + j;
    float x = W2[(size_t)k * 96 + f];
    unsigned u = __float_as_uint(x);
    unsigned h = (u + 0x7fffu + ((u >> 16) & 1u)) & 0xffff0000u;
    float res = x - __uint_as_float(h);
    unsigned v = __float_as_uint(res);
    Fhi[idx] = (short)(h >> 16);
    Flo[idx] = (short)((v + 0x7fffu + ((v >> 16) & 1u)) >> 16);
}
// ---------- prep: y0 = rel_bias @ Wr (fp32) ----------
__global__ __launch_bounds__(NT, 1) void y0_kernel(const float* __restrict__ rel_bias,
                                                   const float* __restrict__ Wr,
                                                   float* __restrict__ y0) {
    __shared__ float s[NT];
    const int n = blockIdx.x;
    const int tid = threadIdx.x;
    const int r = tid % 96, p = tid / 96;
    const float* rb = rel_bias + n * 9216;
    float acc = 0.f;
    for (int i = p * 1152; i < (p + 1) * 1152; ++i)
        acc += rb[i] * Wr[(size_t)i * 96 + r];
    s[tid] = acc;
    __syncthreads();
    if (tid < 96) {
        float tot = 0.f;
        for (int q = 0; q < 8; ++q) tot += s[q * 96 + tid];
        y0[n * 96 + tid] = tot;
    }
}

// ---------------- main scan: one block per batch ----------------
__global__ __launch_bounds__(NT, 3) void stm_kernel(
    const float* __restrict__ x, const float* __restrict__ Wqkv, const float* __restrict__ bqkv,
    const float* __restrict__ ln_g, const float* __restrict__ ln_b,
    const float* __restrict__ a1p, const float* __restrict__ a2p, const float* __restrict__ a3p,
    const float* __restrict__ b2, const float* __restrict__ br,
    const float* __restrict__ W3, const float* __restrict__ b3,
    const float* __restrict__ item_bias, const float* __restrict__ rel_bias,
    const float* __restrict__ y0g,
    const short* __restrict__ WrH, const short* __restrict__ WrL,
    const short* __restrict__ W2H, const short* __restrict__ W2L,
    float* __restrict__ out)
{
    __shared__ float s_Mi[9216];
    __shared__ float s_S[9216];
    __shared__ float s_Q[2304];
    __shared__ __attribute__((aligned(16))) unsigned s_scr[6912]; // qkv | partials | 2 chunk bufs | reductions
    __shared__ __attribute__((aligned(16))) unsigned s_tP[8 * TPs]; // packed-split t: [j][n*96+d]
    __shared__ float s_tsum[768];
    __shared__ float s_v[768];
    __shared__ float s_G[768];
    __shared__ float s_y[768];
    __shared__ float s_xt[96];
    __shared__ float s_xtWq[24];
    __shared__ float s_GWq[192];
    __shared__ float s_b2Wq[24];
    __shared__ float s_Vtr[96];
    __shared__ float s_br[96];
    __shared__ float s_red[32];
    __shared__ float s_mu, s_rstd;

    const int tid = threadIdx.x;
    const int b = blockIdx.x;
    const int wv = tid >> 6, lane = tid & 63, col = lane & 15, grp = lane >> 4;
    const float a1 = a1p[0], a2 = a2p[0], a3 = a3p[0];
    float* scr = (float*)s_scr;

    // build-phase thread mapping: n_h = head row, k0 = 4 consecutive k's within chunk
    const int bn = tid & 7;          // n (A row)
    const int bg = tid >> 3;         // 0..95
    const int bk0 = bg * 4;          // k_local in [0,384)
    const int bdl = bk0 / 96;        // d_local 0..3
    const int be0 = bk0 % 96;
    const int bkb = bk0 >> 5;        // kb_local 0..11
    const int bj0 = bk0 & 31;        // dword offset within kb (0,4,..,28)

    // ---- init ----
    for (int i = tid; i < 9216; i += NT) {
        s_Mi[i] = item_bias[i];
        float ss = 0.f;
        for (int n = 0; n < 8; ++n) ss += rel_bias[n * 9216 + i];
        s_S[i] = ss;
    }
    s_y[tid] = y0g[tid];
    if (tid < 96) s_br[tid] = br[tid];
    for (int pp = 0; pp < 3; ++pp) {
        int o = tid + NT * pp; int i = o / C3, c = o % C3;
        float acc = 0.f;
        const float* ib = item_bias + i * 96;
        for (int k = 0; k < 96; ++k) acc += ib[k] * Wqkv[k * C3 + c];
        s_Q[o] = acc;
    }
    { int c = tid % C3, p = tid / C3; float acc = 0.f;
      for (int k = 3 * p; k < 3 * p + 3; ++k) acc += b2[k] * Wqkv[k * C3 + c];
      scr[tid] = acc; }
    __syncthreads();
    if (tid < C3) { float a = 0.f; for (int p = 0; p < 32; ++p) a += scr[p * C3 + tid]; s_b2Wq[tid] = a; }
    __syncthreads();

    for (int t = 0; t < T_; ++t) {
        // 1: xt
        if (tid < 96) s_xt[tid] = x[((size_t)t * B_ + b) * 96 + tid];
        __syncthreads();
        // 2: Mi += xt xt^T ; xtWq partials
        for (int p = 0; p < 12; ++p) { int i = tid + NT * p; s_Mi[i] += s_xt[i / 96] * s_xt[i % 96]; }
        { int c = tid % C3, p = tid / C3; float acc = 0.f;
          for (int k = 3 * p; k < 3 * p + 3; ++k) acc += s_xt[k] * Wqkv[k * C3 + c];
          scr[tid] = acc; }
        __syncthreads();
        // 3: xtWq final ; Vtr partials
        if (tid < C3) { float a = 0.f; for (int p = 0; p < 32; ++p) a += scr[p * C3 + tid]; s_xtWq[tid] = a; }
        { int f = tid % 96, p = tid / 96; float acc = 0.f;
          for (int d = p * 12; d < p * 12 + 12; ++d) acc += s_Mi[d * 96 + f] * s_S[d * 96 + f];
          scr[768 + tid] = acc; }
        __syncthreads();
        // 4: Vtr final ; Q += xt ⊗ xtWq
        if (tid < 96) { float a = 0.f; for (int p = 0; p < 8; ++p) a += scr[768 + p * 96 + tid]; s_Vtr[tid] = a; }
        for (int pp = 0; pp < 3; ++pp) { int o = tid + NT * pp; int i = o / C3, c = o % C3;
            s_Q[o] += s_xt[i] * s_xtWq[c]; }
        __syncthreads();
        // 5: qkv_pre -> scr[0..2304) + LN sums
        {
            float ls = 0.f, lq = 0.f;
            for (int pp = 0; pp < 3; ++pp) {
                int o = tid + NT * pp; int i = o / C3, c = o % C3;
                float q = s_Q[o] + a2 * s_Vtr[i] * s_xtWq[c] + bqkv[c];
                scr[o] = q; ls += q; lq += q * q;
            }
            for (int off = 32; off > 0; off >>= 1) { ls += __shfl_down(ls, off); lq += __shfl_down(lq, off); }
            if (lane == 0) { s_red[wv] = ls; s_red[16 + wv] = lq; }
        }
        __syncthreads();
        if (tid == 0) {
            float S = 0.f, Qs = 0.f;
            for (int w = 0; w < 12; ++w) { S += s_red[w]; Qs += s_red[16 + w]; }
            float mu = S * (1.0f / 2304.f);
            float var = Qs * (1.0f / 2304.f) - mu * mu;
            s_mu = mu; s_rstd = rsqrtf(var + EPS_);
        }
        __syncthreads();
        // 7: LN apply
        { float mu = s_mu, rs = s_rstd;
          for (int pp = 0; pp < 3; ++pp) { int o = tid + NT * pp;
              scr[o] = (scr[o] - mu) * rs * ln_g[o] + ln_b[o]; } }
        __syncthreads();
        // 8: v copy + t (fp32 tanh, exact fp32 tsum, packed-split store)
        { int j = tid / 96, e = tid % 96; s_v[tid] = scr[e * C3 + 16 + j]; }
        {
            int j = tid / 96, d = tid % 96;
            float kk = scr[d * C3 + 8 + j];
            float ts = 0.f;
#pragma unroll
            for (int n = 0; n < 8; ++n) {
                float tv = tanhf(scr[d * C3 + n] * kk);
                ts += tv;
                s_tP[j * TPs + n * 96 + d] = packsplit(tv);
            }
            s_tsum[j * 96 + d] = ts;
        }
        __syncthreads();
        // 9: G-GEMM via fragment-major W2 planes (4-term split, recurrence-critical)
        {
            const int rt = wv % 6, kh = wv / 6;
            f32x4 accG = {0.f, 0.f, 0.f, 0.f};
#pragma unroll
            for (int s2 = 0; s2 < 12; ++s2) {
                int kb = kh * 12 + s2;
                unsigned pa[8] = {0,0,0,0,0,0,0,0};
                if (col < 8) {
                    const uint4* q0 = (const uint4*)&s_tP[col * TPs + kb * 32 + grp * 8];
                    uint4 x0 = q0[0], x1 = q0[1];
                    pa[0]=x0.x; pa[1]=x0.y; pa[2]=x0.z; pa[3]=x0.w;
                    pa[4]=x1.x; pa[5]=x1.y; pa[6]=x1.z; pa[7]=x1.w;
                }
                bf16x8 ah, al; unpack_frags(pa, ah, al);
                int fo = ((rt * 24 + kb) * 64 + lane) * 8;
                bf16x8 bh = *(const bf16x8*)&W2H[fo];
                bf16x8 bl = *(const bf16x8*)&W2L[fo];
                accG = mfma16(ah, bh, accG);
                accG = mfma16(al, bh, accG);
                accG = mfma16(ah, bl, accG);
                accG = mfma16(al, bl, accG);
            }
            if (kh == 0 && grp < 2) {
#pragma unroll
                for (int reg = 0; reg < 4; ++reg)
                    s_G[(grp * 4 + reg) * 96 + rt * 16 + col] = accG[reg];
            }
            __syncthreads();
            if (kh == 1 && grp < 2) {
#pragma unroll
                for (int reg = 0; reg < 4; ++reg)
                    s_G[(grp * 4 + reg) * 96 + rt * 16 + col] += accG[reg];
            }
        }
        __syncthreads();
        // 10: GWq partials + S/Mi updates
        { int oo = tid % 192, p = tid / 192; int jg = oo / C3, cc = oo % C3;
          float a = 0.f;
          for (int f = p * 24; f < p * 24 + 24; ++f) a += s_G[jg * 96 + f] * Wqkv[f * C3 + cc];
          scr[tid] = a; }
        {
            int de = tid >> 3, ef0 = (tid & 7) * 12;
            float tj[8], vj[8];
#pragma unroll
            for (int j = 0; j < 8; ++j) { tj[j] = s_tsum[j * 96 + de]; vj[j] = s_v[j * 96 + de]; }
            float sn[12], r2[12];
#pragma unroll
            for (int ii = 0; ii < 12; ++ii) { sn[ii] = 0.f; r2[ii] = b2[ef0 + ii]; }
#pragma unroll
            for (int j = 0; j < 8; ++j) {
                const float4* vp = (const float4*)&s_v[j * 96 + ef0];
                const float4* gp = (const float4*)&s_G[j * 96 + ef0];
#pragma unroll
                for (int q4 = 0; q4 < 3; ++q4) {
                    float4 vv = vp[q4], gg = gp[q4];
                    sn[q4 * 4 + 0] += tj[j] * vv.x; sn[q4 * 4 + 1] += tj[j] * vv.y;
                    sn[q4 * 4 + 2] += tj[j] * vv.z; sn[q4 * 4 + 3] += tj[j] * vv.w;
                    r2[q4 * 4 + 0] += vj[j] * gg.x; r2[q4 * 4 + 1] += vj[j] * gg.y;
                    r2[q4 * 4 + 2] += vj[j] * gg.z; r2[q4 * 4 + 3] += vj[j] * gg.w;
                }
            }
#pragma unroll
            for (int ii = 0; ii < 12; ++ii) {
                int idx = de * 96 + ef0 + ii;
                s_S[idx] = a1 * s_S[idx] + sn[ii];
                s_Mi[idx] += a3 * r2[ii];
            }
        }
        __syncthreads();
        // 11: GWq final
        if (tid < 192) s_GWq[tid] = scr[tid] + scr[192 + tid] + scr[384 + tid] + scr[576 + tid];
        __syncthreads();
        // 12: Q += a3*(v^T GWq + b2Wq)
        for (int pp = 0; pp < 3; ++pp) {
            int o = tid + NT * pp; int i = o / C3, c = o % C3;
            float a = s_b2Wq[c];
#pragma unroll
            for (int j = 0; j < 8; ++j) a += s_v[j * 96 + i] * s_GWq[j * C3 + c];
            s_Q[o] += a3 * a;
        }
        // ---- heavy: y += R0 @ Wr. 24 chunks x 4 d's, double-buffered, 1 barrier/chunk ----
        f32x4 acc[6];
#pragma unroll
        for (int rt = 0; rt < 6; ++rt) acc[rt] = (f32x4){0.f, 0.f, 0.f, 0.f};

        // prefill chunk 0 into buf0
        {
            float r0 = 0.f, r1 = 0.f, r2v = 0.f, r3 = 0.f;
            int d = bdl;   // ch=0
#pragma unroll
            for (int j = 0; j < 8; ++j) {
                float tj = unpack2f(s_tP[j * TPs + bn * 96 + d]);
                float4 v4 = *(const float4*)&s_v[j * 96 + be0];
                r0 += tj * v4.x; r1 += tj * v4.y; r2v += tj * v4.z; r3 += tj * v4.w;
            }
            uint4 w; w.x = packsplit(r0); w.y = packsplit(r1); w.z = packsplit(r2v); w.w = packsplit(r3);
            *(uint4*)&s_scr[bkb * KBR + bn * CS + bj0] = w;
        }
        for (int ch = 0; ch < 24; ++ch) {
            __syncthreads();
            // consume buf[ch&1]: wave wv handles kb_local = wv
            {
                const unsigned* buf = s_scr + (ch & 1) * CBS;
                unsigned pa[8] = {0,0,0,0,0,0,0,0};
                if (col < 8) {
                    const uint4* q0 = (const uint4*)&buf[wv * KBR + col * CS + grp * 8];
                    uint4 x0 = q0[0], x1 = q0[1];
                    pa[0]=x0.x; pa[1]=x0.y; pa[2]=x0.z; pa[3]=x0.w;
                    pa[4]=x1.x; pa[5]=x1.y; pa[6]=x1.z; pa[7]=x1.w;
                }
                bf16x8 ah, al; unpack_frags(pa, ah, al);
                const int kbg = ch * 12 + wv;
                const int fbase = (kbg * 64 + lane) * 8;
#pragma unroll
                for (int rt = 0; rt < 6; ++rt) {
                    int fo = rt * 147456 + fbase;   // rt*288*64*8
                    bf16x8 bh = *(const bf16x8*)&WrH[fo];
                    bf16x8 bl = *(const bf16x8*)&WrL[fo];
                    acc[rt] = mfma16(ah, bh, acc[rt]);
                    acc[rt] = mfma16(al, bh, acc[rt]);
                    acc[rt] = mfma16(ah, bl, acc[rt]);
                }
            }
            // build chunk ch+1 into buf[(ch+1)&1]
            if (ch < 23) {
                float r0 = 0.f, r1 = 0.f, r2v = 0.f, r3 = 0.f;
                int d = (ch + 1) * 4 + bdl;
#pragma unroll
                for (int j = 0; j < 8; ++j) {
                    float tj = unpack2f(s_tP[j * TPs + bn * 96 + d]);
                    float4 v4 = *(const float4*)&s_v[j * 96 + be0];
                    r0 += tj * v4.x; r1 += tj * v4.y; r2v += tj * v4.z; r3 += tj * v4.w;
                }
                uint4 w; w.x = packsplit(r0); w.y = packsplit(r1); w.z = packsplit(r2v); w.w = packsplit(r3);
                *(uint4*)&s_scr[((ch + 1) & 1) * CBS + bkb * KBR + bn * CS + bj0] = w;
            }
        }
        __syncthreads();
        // reduce 12 wave-partials (rows 0..7) into y
        if (wv < 6 && grp < 2) {
#pragma unroll
            for (int rt = 0; rt < 6; ++rt)
#pragma unroll
                for (int reg = 0; reg < 4; ++reg)
                    scr[(wv * 8 + grp * 4 + reg) * 96 + rt * 16 + col] = acc[rt][reg];
        }
        __syncthreads();
        if (wv >= 6 && grp < 2) {
#pragma unroll
            for (int rt = 0; rt < 6; ++rt)
#pragma unroll
                for (int reg = 0; reg < 4; ++reg)
                    scr[((wv - 6) * 8 + grp * 4 + reg) * 96 + rt * 16 + col] += acc[rt][reg];
        }
        __syncthreads();
        { int n = tid / 96, r = tid % 96; float a = 0.f;
          for (int w = 0; w < 6; ++w) a += scr[(w * 8 + n) * 96 + r];
          s_y[tid] = a1 * s_y[tid] + a; }
        __syncthreads();
        // out = (y + br) @ W3 + b3
        { int o = tid & 63, qq = tid >> 6; float a = 0.f;
          for (int i = qq * 64; i < qq * 64 + 64; ++i)
              a += (s_y[i] + s_br[i % 96]) * W3[(size_t)i * 64 + o];
          scr[tid] = a; }
        __syncthreads();
        if (tid < 64) {
            float a = b3[tid];
            for (int q = 0; q < 12; ++q) a += scr[q * 64 + tid];
            out[((size_t)t * B_ + b) * OUT_ + tid] = a;
        }
        __syncthreads();
    }
}

extern "C" void kernel_launch(void* const* d_in, const int* in_sizes, int n_in,
                              void* d_out, int out_size, void* d_ws, size_t ws_size,
                              hipStream_t stream) {
    const float* x         = (const float*)d_in[0];
    const float* Wqkv      = (const float*)d_in[1];
    const float* bqkv      = (const float*)d_in[2];
    const float* ln_g      = (const float*)d_in[3];
    const float* ln_b      = (const float*)d_in[4];
    const float* a1        = (const float*)d_in[5];
    const float* a2        = (const float*)d_in[6];
    const float* a3        = (const float*)d_in[7];
    const float* W2        = (const float*)d_in[8];
    const float* b2        = (const float*)d_in[9];
    const float* Wr        = (const float*)d_in[10];
    const float* br        = (const float*)d_in[11];
    const float* W3        = (const float*)d_in[12];
    const float* b3        = (const float*)d_in[13];
    const float* item_bias = (const float*)d_in[14];
    const float* rel_bias  = (const float*)d_in[15];
    float* out = (float*)d_out;

    char* ws = (char*)d_ws;
    short* WrH = (short*)ws;                               // 1,769,472 B
    short* WrL = (short*)(ws + 1769472);                   // 1,769,472 B
    short* W2H = (short*)(ws + 2 * 1769472);               //   147,456 B
    short* W2L = (short*)(ws + 2 * 1769472 + 147456);      //   147,456 B
    float* y0  = (float*)(ws + 2 * 1769472 + 2 * 147456);  //     3,072 B

    hipLaunchKernelGGL(prep_wrf, dim3(3456), dim3(256), 0, stream, Wr, WrH, WrL);
    hipLaunchKernelGGL(prep_w2f, dim3(288), dim3(256), 0, stream, W2, W2H, W2L);
    hipLaunchKernelGGL(y0_kernel, dim3(8), dim3(NT), 0, stream, rel_bias, Wr, y0);
    hipLaunchKernelGGL(stm_kernel, dim3(B_), dim3(NT), 0, stream,
                       x, Wqkv, bqkv, ln_g, ln_b, a1, a2, a3,
                       b2, br, W3, b3, item_bias, rel_bias,
                       y0, WrH, WrL, W2H, W2L, out);
}